// Round 7
// baseline (313.953 us; speedup 1.0000x reference)
//
#include <hip/hip_runtime.h>
#include <hip/hip_bf16.h>
#include <math.h>

#define NTOK 8192
#define HD   1024
#define FFND 2048
#define NE   64
#define MTOT 16384   // NTOK * TOPK
#define PER_E 256    // MTOT / NE

typedef __attribute__((ext_vector_type(8))) short bh8;
typedef __attribute__((ext_vector_type(4))) float f4;
typedef unsigned short u16;
typedef unsigned int   u32;

__device__ __forceinline__ u16 f2bf(float f) {
  union { float f; u32 u; } x; x.f = f;
  u32 r = x.u + 0x7fffu + ((x.u >> 16) & 1u);   // round-nearest-even
  return (u16)(r >> 16);
}

__device__ __forceinline__ float bf2f(u16 b) {
  union { u32 u; float f; } x; x.u = ((u32)b) << 16; return x.f;
}

__device__ __forceinline__ u32 pk2(float lo, float hi) {
  __hip_bfloat162 h = __float22bfloat162_rn(make_float2(lo, hi));
  union { __hip_bfloat162 h; u32 u; } c; c.h = h;
  return c.u;
}

// slot -> source token map. scatter_index flat: sidx[t*2+k] = slot.
__global__ void k_build_s2t(const int* __restrict__ sidx, int* __restrict__ s2t) {
  int i = blockIdx.x * 256 + threadIdx.x;   // i in [0, MTOT)
  s2t[sidx[i]] = i >> 1;
}

// Gather + f32->bf16 convert: X[slot][h] = bf16(inputs[s2t[slot]][h])
__global__ void k_gather_x(const float* __restrict__ inp, const int* __restrict__ s2t,
                           u16* __restrict__ X) {
  int idx = blockIdx.x * 256 + threadIdx.x;   // MTOT*HD/8 threads
  int slot = idx >> 7;                        // HD/8 = 128 chunks per row
  int c    = idx & 127;
  const float* src = inp + (size_t)s2t[slot] * HD + c * 8;
  float v[8];
  *(f4*)(v)     = *(const f4*)(src);
  *(f4*)(v + 4) = *(const f4*)(src + 4);
  u32 o[4];
  #pragma unroll
  for (int j = 0; j < 4; ++j) o[j] = pk2(v[2 * j], v[2 * j + 1]);
  *(uint4*)(X + (size_t)slot * HD + c * 8) = *(uint4*)o;
}

// Grouped GEMM, depth-1 prefetch pipeline.
//   A: bf16 [MTOT][K] -> global_load_lds into DOUBLE-buffered As (src pre-swizzled)
//   B: f32 [NE][K][N] -> prefetch to regs, cvt_pk -> single Bs after MFMA
//   BN=128: waves 4x2, per-wave 64x64 (GEMM1). BN=64: per-wave 64x32 (GEMM2,
//   NB=16 so co-resident act panels fit per-XCD L2).
// GELU=true: write bf16 act.  GELU=false: write bf16 partials to redout.
template<int K, int N, int BN, bool GELU>
__global__ __launch_bounds__(512, 4)
void moe_gemm(const u16* __restrict__ Abf, const float* __restrict__ Bf,
              u16* __restrict__ outp)
{
  constexpr int BM = 256, BK = 64;
  constexpr int NB = N / BN;                  // n0-blocks per expert
  constexpr int NT = K / BK;                  // K-steps
  constexpr int NF = BN / 32;                 // b-fragments per wave
  constexpr int BITER = BN / 64;              // B staging iterations
  constexpr int ABYTES = BM * 128;            // one As buffer
  __shared__ __align__(16) char lds[2 * ABYTES + BN * 128];
  char* Bs = lds + 2 * ABYTES;     // Bs[n]: 64 bf16 (k-contig), chunk XOR (n&7)

  // XCD swizzle, n0 innermost: co-resident blocks on an XCD share A panels.
  const int d = blockIdx.y * NB + blockIdx.x;
  const int x = d & 7, j = d >> 3;
  const int e  = x * (NE / 8) + j / NB;
  const int n0 = (j % NB) * BN;
  const int row0 = e * PER_E;
  const int tid  = threadIdx.x;
  const int lane = tid & 63, wid = tid >> 6;
  const int wr   = wid >> 1, wc = wid & 1;    // 4x2 waves: 64 x (BN/2) each

  const u16*   Arow = Abf + (size_t)row0 * K;
  const float* Bsrc = Bf + (size_t)e * K * N + n0;

  // A-stage: 256x64 bf16 via global_load_lds, dest linear, src chunk XOR'd
  auto stageA = [&](int buf, int k0) {
    char* dst = lds + buf * ABYTES;
    #pragma unroll
    for (int i = 0; i < 4; ++i) {
      int c = i * 512 + tid;
      int r = c >> 3, kc = c & 7;
      int kswz = kc ^ (r & 7);
      __builtin_amdgcn_global_load_lds(
          (const void*)(Arow + (size_t)r * K + k0 + kswz * 8),
          (void*)(dst + c * 16), 16, 0, 0);
    }
  };
  // B-prefetch: strided f32 loads into regs (8 per chunk-iter)
  auto loadB = [&](float* br, int k0) {
    #pragma unroll
    for (int i = 0; i < BITER; ++i) {
      int c = i * 512 + tid;
      int n = c & (BN - 1), kc = c / BN;
      const float* p = Bsrc + (size_t)(k0 + kc * 8) * N + n;
      #pragma unroll
      for (int jj = 0; jj < 8; ++jj) br[i * 8 + jj] = p[(size_t)jj * N];
    }
  };
  // B-publish: cvt_pk pairs -> Bs[n][k] (k-transposed, XOR-swizzled)
  auto writeB = [&](const float* br) {
    #pragma unroll
    for (int i = 0; i < BITER; ++i) {
      int c = i * 512 + tid;
      int n = c & (BN - 1), kc = c / BN;
      u32 q[4];
      #pragma unroll
      for (int jj = 0; jj < 4; ++jj) q[jj] = pk2(br[i * 8 + 2 * jj], br[i * 8 + 2 * jj + 1]);
      *(uint4*)(Bs + n * 128 + ((kc * 16) ^ ((n & 7) << 4))) = *(uint4*)q;
    }
  };

  f4 acc[4][NF] = {};
  float breg[BITER * 8];

  // ---- prologue: stage tile 0 ----
  stageA(0, 0);
  loadB(breg, 0);
  writeB(breg);
  asm volatile("s_waitcnt vmcnt(0) lgkmcnt(0)" ::: "memory");
  __builtin_amdgcn_sched_barrier(0);
  __builtin_amdgcn_s_barrier();
  __builtin_amdgcn_sched_barrier(0);

  int cur = 0;
  for (int t = 0; t < NT; ++t) {
    const char* As = lds + cur * ABYTES;
    // ---- issue next tile's loads (stay in flight through the MFMAs) ----
    if (t + 1 < NT) {
      stageA(cur ^ 1, (t + 1) * BK);
      loadB(breg, (t + 1) * BK);
    }
    // ---- compute tile t: 2 kk-halves x 4xNF MFMA 16x16x32 ----
    __builtin_amdgcn_s_setprio(1);
    #pragma unroll
    for (int kk = 0; kk < 2; ++kk) {
      int kByte = kk * 64 + ((lane >> 4) << 4);
      bh8 a[4], b[NF];
      #pragma unroll
      for (int m = 0; m < 4; ++m) {
        int r = wr * 64 + m * 16 + (lane & 15);
        a[m] = *(const bh8*)(As + r * 128 + (kByte ^ ((r & 7) << 4)));
      }
      #pragma unroll
      for (int n = 0; n < NF; ++n) {
        int r = wc * (NF * 16) + n * 16 + (lane & 15);
        b[n] = *(const bh8*)(Bs + r * 128 + (kByte ^ ((r & 7) << 4)));
      }
      #pragma unroll
      for (int m = 0; m < 4; ++m)
        #pragma unroll
        for (int n = 0; n < NF; ++n)
          acc[m][n] = __builtin_amdgcn_mfma_f32_16x16x32_bf16(a[m], b[n], acc[m][n], 0, 0, 0);
    }
    __builtin_amdgcn_s_setprio(0);
    // ---- barrier 1: everyone done READING Bs (no counter drain) ----
    __builtin_amdgcn_s_barrier();
    __builtin_amdgcn_sched_barrier(0);
    if (t + 1 < NT) {
      writeB(breg);
      asm volatile("s_waitcnt vmcnt(0) lgkmcnt(0)" ::: "memory");  // A in LDS, Bs written
      __builtin_amdgcn_sched_barrier(0);
      __builtin_amdgcn_s_barrier();   // publish As[nxt] + Bs(t+1)
      __builtin_amdgcn_sched_barrier(0);
      cur ^= 1;
    }
  }

  // ---- epilogue ----
  // C layout (m89): col = lane&15, row = (lane>>4)*4 + j
  #pragma unroll
  for (int m = 0; m < 4; ++m) {
    #pragma unroll
    for (int n = 0; n < NF; ++n) {
      int rowb = wr * 64 + m * 16 + ((lane >> 4) << 2);
      int col  = n0 + wc * (NF * 16) + n * 16 + (lane & 15);
      #pragma unroll
      for (int jj = 0; jj < 4; ++jj) {
        float xv = acc[m][n][jj];
        if (GELU) {
          // tanh-form GELU: y/(1+exp(-2u)), u = 0.79788456(y + 0.044715 y^3)
          float y = fminf(fmaxf(xv, -8.f), 8.f);
          float u = 0.7978845608f * (y + 0.044715f * y * y * y);
          float t2 = __expf(-2.f * u);
          float g = __fdividef(y, 1.f + t2);
          outp[(size_t)(row0 + rowb + jj) * N + col] = f2bf(g);
        } else {
          outp[(size_t)(row0 + rowb + jj) * N + col] = f2bf(xv);
        }
      }
    }
  }
}

// out[t][:] = h2[sidx[2t]][:] + h2[sidx[2t+1]][:]   (h2 bf16; out f32)
__global__ void k_reduce(const u16* __restrict__ h2, const int* __restrict__ sidx,
                         float* __restrict__ out) {
  int t = blockIdx.x;
  int c = threadIdx.x;                        // 256 threads x 4 floats = 1024
  const u16* r0 = h2 + (size_t)sidx[2 * t] * HD + c * 4;
  const u16* r1 = h2 + (size_t)sidx[2 * t + 1] * HD + c * 4;
  u16 a0[4], a1[4];
  *(uint2*)a0 = *(const uint2*)r0;
  *(uint2*)a1 = *(const uint2*)r1;
  f4 s;
  #pragma unroll
  for (int jj = 0; jj < 4; ++jj) s[jj] = bf2f(a0[jj]) + bf2f(a1[jj]);
  *(f4*)(out + (size_t)t * HD + c * 4) = s;
}

extern "C" void kernel_launch(void* const* d_in, const int* in_sizes, int n_in,
                              void* d_out, int out_size, void* d_ws, size_t ws_size,
                              hipStream_t stream) {
  const float* inp  = (const float*)d_in[0];
  const float* w1   = (const float*)d_in[1];
  const float* w2   = (const float*)d_in[2];
  const int*   sidx = (const int*)d_in[3];
  float* out = (float*)d_out;

  char* ws   = (char*)d_ws;
  int*   s2t = (int*)ws;                                          // 64 KB
  u16*   X   = (u16*)(ws + (1 << 20));                            // 32 MB bf16 [MTOT][HD]
  u16*   act = (u16*)(ws + (1 << 20) + (32u << 20));              // 64 MB bf16 [MTOT][FFND]
  u16*   h2  = (u16*)(ws + (1 << 20) + (96u << 20));              // 32 MB bf16 [MTOT][HD]

  k_build_s2t<<<MTOT / 256, 256, 0, stream>>>(sidx, s2t);
  k_gather_x<<<(MTOT * (HD / 8)) / 256, 256, 0, stream>>>(inp, s2t, X);
  moe_gemm<HD, FFND, 128, true><<<dim3(FFND / 128, NE), 512, 0, stream>>>(X, w1, act);
  moe_gemm<FFND, HD, 64, false><<<dim3(HD / 64, NE), 512, 0, stream>>>(act, w2, h2);
  k_reduce<<<NTOK, 256, 0, stream>>>(h2, sidx, out);
}

// Round 8
// 302.302 us; speedup vs baseline: 1.0385x; 1.0385x over previous
//
#include <hip/hip_runtime.h>
#include <hip/hip_bf16.h>
#include <math.h>

#define NTOK 8192
#define HD   1024
#define FFND 2048
#define NE   64
#define MTOT 16384   // NTOK * TOPK
#define PER_E 256    // MTOT / NE

typedef __attribute__((ext_vector_type(8))) short bh8;
typedef __attribute__((ext_vector_type(4))) float f4;
typedef unsigned short u16;
typedef unsigned int   u32;

__device__ __forceinline__ u16 f2bf(float f) {
  union { float f; u32 u; } x; x.f = f;
  u32 r = x.u + 0x7fffu + ((x.u >> 16) & 1u);   // round-nearest-even
  return (u16)(r >> 16);
}

__device__ __forceinline__ float bf2f(u16 b) {
  union { u32 u; float f; } x; x.u = ((u32)b) << 16; return x.f;
}

__device__ __forceinline__ u32 pk2(float lo, float hi) {
  __hip_bfloat162 h = __float22bfloat162_rn(make_float2(lo, hi));
  union { __hip_bfloat162 h; u32 u; } c; c.h = h;
  return c.u;
}

// slot -> source token map. scatter_index flat: sidx[t*2+k] = slot.
__global__ void k_build_s2t(const int* __restrict__ sidx, int* __restrict__ s2t) {
  int i = blockIdx.x * 256 + threadIdx.x;   // i in [0, MTOT)
  s2t[sidx[i]] = i >> 1;
}

// Gather + f32->bf16 convert: X[slot][h] = bf16(inputs[s2t[slot]][h])
__global__ void k_gather_x(const float* __restrict__ inp, const int* __restrict__ s2t,
                           u16* __restrict__ X) {
  int idx = blockIdx.x * 256 + threadIdx.x;   // MTOT*HD/8 threads
  int slot = idx >> 7;                        // HD/8 = 128 chunks per row
  int c    = idx & 127;
  const float* src = inp + (size_t)s2t[slot] * HD + c * 8;
  float v[8];
  *(f4*)(v)     = *(const f4*)(src);
  *(f4*)(v + 4) = *(const f4*)(src + 4);
  u32 o[4];
  #pragma unroll
  for (int j = 0; j < 4; ++j) o[j] = pk2(v[2 * j], v[2 * j + 1]);
  *(uint4*)(X + (size_t)slot * HD + c * 8) = *(uint4*)o;
}

// Grouped GEMM, depth-1 prefetch with COUNTED vmcnt (never drains to 0):
//   per iter: issue loadB(t+1) [16 VMEM, older] then stageA(t+1) [4 VMEM, newest];
//   vmcnt(20) before MFMA(t) waits only A(t); vmcnt(4) before writeB waits only
//   B(t+1), keeping A(t+1) in flight ACROSS barrier2.
// GELU=true: write bf16 act.  GELU=false: write bf16 partials.
template<int K, int N, bool GELU>
__global__ __launch_bounds__(512, 4)
void moe_gemm(const u16* __restrict__ Abf, const float* __restrict__ Bf,
              u16* __restrict__ outp)
{
  constexpr int BM = 256, BN = 128, BK = 64;
  constexpr int NB = N / BN;                  // n0-blocks per expert
  constexpr int NT = K / BK;                  // K-steps
  constexpr int ABYTES = BM * 128;            // one As buffer (32 KB)
  __shared__ __align__(16) char lds[2 * ABYTES + BN * 128];  // 80 KB
  char* Bs = lds + 2 * ABYTES;     // Bs[n]: 64 bf16 (k-contig), chunk XOR (n&7)

  // XCD swizzle, n0 innermost: co-resident blocks on an XCD share A panels.
  const int d = blockIdx.y * NB + blockIdx.x;
  const int x = d & 7, j = d >> 3;
  const int e  = x * (NE / 8) + j / NB;
  const int n0 = (j % NB) * BN;
  const int row0 = e * PER_E;
  const int tid  = threadIdx.x;
  const int lane = tid & 63, wid = tid >> 6;
  const int wr   = wid >> 1, wc = wid & 1;    // 4x2 waves of 64x64

  const u16*   Arow = Abf + (size_t)row0 * K;
  const float* Bsrc = Bf + (size_t)e * K * N + n0;

  // A-stage: 256x64 bf16 via global_load_lds, dest linear, src chunk XOR'd
  auto stageA = [&](int buf, int k0) {
    char* dst = lds + buf * ABYTES;
    #pragma unroll
    for (int i = 0; i < 4; ++i) {
      int c = i * 512 + tid;
      int r = c >> 3, kc = c & 7;
      int kswz = kc ^ (r & 7);
      __builtin_amdgcn_global_load_lds(
          (const void*)(Arow + (size_t)r * K + k0 + kswz * 8),
          (void*)(dst + c * 16), 16, 0, 0);
    }
  };
  // B-prefetch: 16 strided f32 loads into regs
  auto loadB = [&](float* br, int k0) {
    #pragma unroll
    for (int i = 0; i < 2; ++i) {
      int c = i * 512 + tid;
      int n = c & 127, kc = c >> 7;
      const float* p = Bsrc + (size_t)(k0 + kc * 8) * N + n;
      #pragma unroll
      for (int jj = 0; jj < 8; ++jj) br[i * 8 + jj] = p[(size_t)jj * N];
    }
  };
  // B-publish: cvt_pk pairs -> Bs[n][k] (k-transposed, XOR-swizzled)
  auto writeB = [&](const float* br) {
    #pragma unroll
    for (int i = 0; i < 2; ++i) {
      int c = i * 512 + tid;
      int n = c & 127, kc = c >> 7;
      u32 q[4];
      #pragma unroll
      for (int jj = 0; jj < 4; ++jj) q[jj] = pk2(br[i * 8 + 2 * jj], br[i * 8 + 2 * jj + 1]);
      *(uint4*)(Bs + n * 128 + ((kc * 16) ^ ((n & 7) << 4))) = *(uint4*)q;
    }
  };

  f4 acc[4][4] = {};
  float breg[16];

  // ---- prologue: B(0) -> Bs; A(0) stays in flight across the barrier ----
  loadB(breg, 0);
  __builtin_amdgcn_sched_barrier(0);
  stageA(0, 0);
  asm volatile("s_waitcnt vmcnt(4)" ::: "memory");   // B(0) regs ready
  __builtin_amdgcn_sched_barrier(0);
  writeB(breg);
  asm volatile("s_waitcnt lgkmcnt(0)" ::: "memory");
  __builtin_amdgcn_sched_barrier(0);
  __builtin_amdgcn_s_barrier();
  __builtin_amdgcn_sched_barrier(0);

  int cur = 0;
  for (int t = 0; t < NT; ++t) {
    const char* As = lds + cur * ABYTES;
    // ---- issue next tile's loads: B older, A newest ----
    if (t + 1 < NT) {
      loadB(breg, (t + 1) * BK);
      __builtin_amdgcn_sched_barrier(0);
      stageA(cur ^ 1, (t + 1) * BK);
      asm volatile("s_waitcnt vmcnt(20)" ::: "memory");  // A(t) landed; 20 fly
    } else {
      asm volatile("s_waitcnt vmcnt(0)" ::: "memory");   // tail: A(t) landed
    }
    __builtin_amdgcn_sched_barrier(0);
    // ---- compute tile t: 2 kk-halves x 4x4 MFMA 16x16x32 ----
    __builtin_amdgcn_s_setprio(1);
    #pragma unroll
    for (int kk = 0; kk < 2; ++kk) {
      int kByte = kk * 64 + ((lane >> 4) << 4);
      bh8 a[4], b[4];
      #pragma unroll
      for (int m = 0; m < 4; ++m) {
        int r = wr * 64 + m * 16 + (lane & 15);
        a[m] = *(const bh8*)(As + r * 128 + (kByte ^ ((r & 7) << 4)));
      }
      #pragma unroll
      for (int n = 0; n < 4; ++n) {
        int r = wc * 64 + n * 16 + (lane & 15);
        b[n] = *(const bh8*)(Bs + r * 128 + (kByte ^ ((r & 7) << 4)));
      }
      #pragma unroll
      for (int m = 0; m < 4; ++m)
        #pragma unroll
        for (int n = 0; n < 4; ++n)
          acc[m][n] = __builtin_amdgcn_mfma_f32_16x16x32_bf16(a[m], b[n], acc[m][n], 0, 0, 0);
    }
    __builtin_amdgcn_s_setprio(0);
    // ---- barrier 1: all waves done reading Bs ----
    __builtin_amdgcn_s_barrier();
    __builtin_amdgcn_sched_barrier(0);
    if (t + 1 < NT) {
      asm volatile("s_waitcnt vmcnt(4)" ::: "memory");   // B(t+1) ready; A(t+1) flies
      __builtin_amdgcn_sched_barrier(0);
      writeB(breg);
      asm volatile("s_waitcnt lgkmcnt(0)" ::: "memory");
      __builtin_amdgcn_sched_barrier(0);
      __builtin_amdgcn_s_barrier();   // barrier 2: Bs(t+1) published, A(t+1) in flight
      __builtin_amdgcn_sched_barrier(0);
      cur ^= 1;
    }
  }

  // ---- epilogue ----
  // C layout (m89): col = lane&15, row = (lane>>4)*4 + j
  #pragma unroll
  for (int m = 0; m < 4; ++m) {
    #pragma unroll
    for (int n = 0; n < 4; ++n) {
      int rowb = wr * 64 + m * 16 + ((lane >> 4) << 2);
      int col  = n0 + wc * 64 + n * 16 + (lane & 15);
      #pragma unroll
      for (int jj = 0; jj < 4; ++jj) {
        float xv = acc[m][n][jj];
        if (GELU) {
          // tanh-form GELU: y/(1+exp(-2u)), u = 0.79788456(y + 0.044715 y^3)
          float y = fminf(fmaxf(xv, -8.f), 8.f);
          float u = 0.7978845608f * (y + 0.044715f * y * y * y);
          float t2 = __expf(-2.f * u);
          float g = __fdividef(y, 1.f + t2);
          outp[(size_t)(row0 + rowb + jj) * N + col] = f2bf(g);
        } else {
          outp[(size_t)(row0 + rowb + jj) * N + col] = f2bf(xv);
        }
      }
    }
  }
}

// out[t][:] = h2[sidx[2t]][:] + h2[sidx[2t+1]][:]   (h2 bf16; out f32)
__global__ void k_reduce(const u16* __restrict__ h2, const int* __restrict__ sidx,
                         float* __restrict__ out) {
  int t = blockIdx.x;
  int c = threadIdx.x;                        // 256 threads x 4 floats = 1024
  const u16* r0 = h2 + (size_t)sidx[2 * t] * HD + c * 4;
  const u16* r1 = h2 + (size_t)sidx[2 * t + 1] * HD + c * 4;
  u16 a0[4], a1[4];
  *(uint2*)a0 = *(const uint2*)r0;
  *(uint2*)a1 = *(const uint2*)r1;
  f4 s;
  #pragma unroll
  for (int jj = 0; jj < 4; ++jj) s[jj] = bf2f(a0[jj]) + bf2f(a1[jj]);
  *(f4*)(out + (size_t)t * HD + c * 4) = s;
}

extern "C" void kernel_launch(void* const* d_in, const int* in_sizes, int n_in,
                              void* d_out, int out_size, void* d_ws, size_t ws_size,
                              hipStream_t stream) {
  const float* inp  = (const float*)d_in[0];
  const float* w1   = (const float*)d_in[1];
  const float* w2   = (const float*)d_in[2];
  const int*   sidx = (const int*)d_in[3];
  float* out = (float*)d_out;

  char* ws   = (char*)d_ws;
  int*   s2t = (int*)ws;                                          // 64 KB
  u16*   X   = (u16*)(ws + (1 << 20));                            // 32 MB bf16 [MTOT][HD]
  u16*   act = (u16*)(ws + (1 << 20) + (32u << 20));              // 64 MB bf16 [MTOT][FFND]
  u16*   h2  = (u16*)(ws + (1 << 20) + (96u << 20));              // 32 MB bf16 [MTOT][HD]

  k_build_s2t<<<MTOT / 256, 256, 0, stream>>>(sidx, s2t);
  k_gather_x<<<(MTOT * (HD / 8)) / 256, 256, 0, stream>>>(inp, s2t, X);
  moe_gemm<HD, FFND, true><<<dim3(FFND / 128, NE), 512, 0, stream>>>(X, w1, act);
  moe_gemm<FFND, HD, false><<<dim3(HD / 128, NE), 512, 0, stream>>>(act, w2, h2);
  k_reduce<<<NTOK, 256, 0, stream>>>(h2, sidx, out);
}

// Round 9
// 292.335 us; speedup vs baseline: 1.0740x; 1.0341x over previous
//
#include <hip/hip_runtime.h>
#include <hip/hip_bf16.h>
#include <math.h>

#define NTOK 8192
#define HD   1024
#define FFND 2048
#define NE   64
#define MTOT 16384   // NTOK * TOPK
#define PER_E 256    // MTOT / NE

typedef __attribute__((ext_vector_type(8))) short bh8;
typedef __attribute__((ext_vector_type(4))) float f4;
typedef unsigned short u16;
typedef unsigned int   u32;

__device__ __forceinline__ u16 f2bf(float f) {
  union { float f; u32 u; } x; x.f = f;
  u32 r = x.u + 0x7fffu + ((x.u >> 16) & 1u);   // round-nearest-even
  return (u16)(r >> 16);
}

__device__ __forceinline__ float bf2f(u16 b) {
  union { u32 u; float f; } x; x.u = ((u32)b) << 16; return x.f;
}

__device__ __forceinline__ u32 pk2(float lo, float hi) {
  __hip_bfloat162 h = __float22bfloat162_rn(make_float2(lo, hi));
  union { __hip_bfloat162 h; u32 u; } c; c.h = h;
  return c.u;
}

// slot -> source token map. scatter_index flat: sidx[t*2+k] = slot.
__global__ void k_build_s2t(const int* __restrict__ sidx, int* __restrict__ s2t) {
  int i = blockIdx.x * 256 + threadIdx.x;   // i in [0, MTOT)
  s2t[sidx[i]] = i >> 1;
}

// Gather + f32->bf16 convert: X[slot][h] = bf16(inputs[s2t[slot]][h])
__global__ void k_gather_x(const float* __restrict__ inp, const int* __restrict__ s2t,
                           u16* __restrict__ X) {
  int idx = blockIdx.x * 256 + threadIdx.x;   // MTOT*HD/8 threads
  int slot = idx >> 7;                        // HD/8 = 128 chunks per row
  int c    = idx & 127;
  const float* src = inp + (size_t)s2t[slot] * HD + c * 8;
  float v[8];
  *(f4*)(v)     = *(const f4*)(src);
  *(f4*)(v + 4) = *(const f4*)(src + 4);
  u32 o[4];
  #pragma unroll
  for (int j = 0; j < 4; ++j) o[j] = pk2(v[2 * j], v[2 * j + 1]);
  *(uint4*)(X + (size_t)slot * HD + c * 8) = *(uint4*)o;
}

// Grouped GEMM, BN=256 (halves A-panel re-read traffic), depth-1 prefetch
// with COUNTED vmcnt: per iter issue loadB(t+1) [32 VMEM, older] then
// stageA(t+1) [4 VMEM, newest]; vmcnt(36) before MFMA(t) waits only A(t);
// vmcnt(4) before writeB waits only B(t+1), A(t+1) flies across barrier2.
// 96 KB LDS -> 1 block/CU (8 waves, 2/SIMD).
// GELU=true: write bf16 act.  GELU=false: write bf16 partials.
template<int K, int N, bool GELU>
__global__ __launch_bounds__(512, 2)
void moe_gemm(const u16* __restrict__ Abf, const float* __restrict__ Bf,
              u16* __restrict__ outp)
{
  constexpr int BM = 256, BN = 256, BK = 64;
  constexpr int NB = N / BN;                  // n0-blocks per expert
  constexpr int NT = K / BK;                  // K-steps
  constexpr int NF = 8;                       // b-fragments per wave (BN/32)
  constexpr int BITER = 4;                    // B staging chunk-iters (BK*BN/8/512)
  constexpr int ABYTES = BM * 128;            // one As buffer (32 KB)
  __shared__ __align__(16) char lds[2 * ABYTES + BN * 128];  // 96 KB
  char* Bs = lds + 2 * ABYTES;     // Bs[n]: 64 bf16 (k-contig), chunk XOR (n&7)

  // XCD swizzle, n0 innermost: co-resident blocks on an XCD share A panels.
  const int d = blockIdx.y * NB + blockIdx.x;
  const int x = d & 7, j = d >> 3;
  const int e  = x * (NE / 8) + j / NB;
  const int n0 = (j % NB) * BN;
  const int row0 = e * PER_E;
  const int tid  = threadIdx.x;
  const int lane = tid & 63, wid = tid >> 6;
  const int wr   = wid >> 1, wc = wid & 1;    // 4x2 waves: 64 x 128 each

  const u16*   Arow = Abf + (size_t)row0 * K;
  const float* Bsrc = Bf + (size_t)e * K * N + n0;

  // A-stage: 256x64 bf16 via global_load_lds, dest linear, src chunk XOR'd
  auto stageA = [&](int buf, int k0) {
    char* dst = lds + buf * ABYTES;
    #pragma unroll
    for (int i = 0; i < 4; ++i) {
      int c = i * 512 + tid;
      int r = c >> 3, kc = c & 7;
      int kswz = kc ^ (r & 7);
      __builtin_amdgcn_global_load_lds(
          (const void*)(Arow + (size_t)r * K + k0 + kswz * 8),
          (void*)(dst + c * 16), 16, 0, 0);
    }
  };
  // B-prefetch: 32 strided f32 loads into regs (8 per chunk-iter)
  auto loadB = [&](float* br, int k0) {
    #pragma unroll
    for (int i = 0; i < BITER; ++i) {
      int c = i * 512 + tid;
      int n = c & (BN - 1), kc = c / BN;      // kc in 0..7
      const float* p = Bsrc + (size_t)(k0 + kc * 8) * N + n;
      #pragma unroll
      for (int jj = 0; jj < 8; ++jj) br[i * 8 + jj] = p[(size_t)jj * N];
    }
  };
  // B-publish: cvt_pk pairs -> Bs[n][k] (k-transposed, XOR-swizzled)
  auto writeB = [&](const float* br) {
    #pragma unroll
    for (int i = 0; i < BITER; ++i) {
      int c = i * 512 + tid;
      int n = c & (BN - 1), kc = c / BN;
      u32 q[4];
      #pragma unroll
      for (int jj = 0; jj < 4; ++jj) q[jj] = pk2(br[i * 8 + 2 * jj], br[i * 8 + 2 * jj + 1]);
      *(uint4*)(Bs + n * 128 + ((kc * 16) ^ ((n & 7) << 4))) = *(uint4*)q;
    }
  };

  f4 acc[4][NF] = {};
  float breg[BITER * 8];

  // ---- prologue: B(0) -> Bs; A(0) stays in flight across the barrier ----
  loadB(breg, 0);
  __builtin_amdgcn_sched_barrier(0);
  stageA(0, 0);
  asm volatile("s_waitcnt vmcnt(4)" ::: "memory");   // B(0) regs ready
  __builtin_amdgcn_sched_barrier(0);
  writeB(breg);
  asm volatile("s_waitcnt lgkmcnt(0)" ::: "memory");
  __builtin_amdgcn_sched_barrier(0);
  __builtin_amdgcn_s_barrier();
  __builtin_amdgcn_sched_barrier(0);

  int cur = 0;
  for (int t = 0; t < NT; ++t) {
    const char* As = lds + cur * ABYTES;
    // ---- issue next tile's loads: B older, A newest ----
    if (t + 1 < NT) {
      loadB(breg, (t + 1) * BK);
      __builtin_amdgcn_sched_barrier(0);
      stageA(cur ^ 1, (t + 1) * BK);
      asm volatile("s_waitcnt vmcnt(36)" ::: "memory");  // A(t) landed; 36 fly
    } else {
      asm volatile("s_waitcnt vmcnt(0)" ::: "memory");   // tail: A(t) landed
    }
    __builtin_amdgcn_sched_barrier(0);
    // ---- compute tile t: 2 kk-halves x 4xNF MFMA 16x16x32 ----
    __builtin_amdgcn_s_setprio(1);
    #pragma unroll
    for (int kk = 0; kk < 2; ++kk) {
      int kByte = kk * 64 + ((lane >> 4) << 4);
      bh8 a[4], b[NF];
      #pragma unroll
      for (int m = 0; m < 4; ++m) {
        int r = wr * 64 + m * 16 + (lane & 15);
        a[m] = *(const bh8*)(As + r * 128 + (kByte ^ ((r & 7) << 4)));
      }
      #pragma unroll
      for (int n = 0; n < NF; ++n) {
        int r = wc * 128 + n * 16 + (lane & 15);
        b[n] = *(const bh8*)(Bs + r * 128 + (kByte ^ ((r & 7) << 4)));
      }
      #pragma unroll
      for (int m = 0; m < 4; ++m)
        #pragma unroll
        for (int n = 0; n < NF; ++n)
          acc[m][n] = __builtin_amdgcn_mfma_f32_16x16x32_bf16(a[m], b[n], acc[m][n], 0, 0, 0);
    }
    __builtin_amdgcn_s_setprio(0);
    // ---- barrier 1: all waves done reading Bs ----
    __builtin_amdgcn_s_barrier();
    __builtin_amdgcn_sched_barrier(0);
    if (t + 1 < NT) {
      asm volatile("s_waitcnt vmcnt(4)" ::: "memory");   // B(t+1) ready; A(t+1) flies
      __builtin_amdgcn_sched_barrier(0);
      writeB(breg);
      asm volatile("s_waitcnt lgkmcnt(0)" ::: "memory");
      __builtin_amdgcn_sched_barrier(0);
      __builtin_amdgcn_s_barrier();   // barrier 2: Bs(t+1) published, A(t+1) in flight
      __builtin_amdgcn_sched_barrier(0);
      cur ^= 1;
    }
  }

  // ---- epilogue ----
  // C layout (m89): col = lane&15, row = (lane>>4)*4 + j
  #pragma unroll
  for (int m = 0; m < 4; ++m) {
    #pragma unroll
    for (int n = 0; n < NF; ++n) {
      int rowb = wr * 64 + m * 16 + ((lane >> 4) << 2);
      int col  = n0 + wc * 128 + n * 16 + (lane & 15);
      #pragma unroll
      for (int jj = 0; jj < 4; ++jj) {
        float xv = acc[m][n][jj];
        if (GELU) {
          // tanh-form GELU: y/(1+exp(-2u)), u = 0.79788456(y + 0.044715 y^3)
          float y = fminf(fmaxf(xv, -8.f), 8.f);
          float u = 0.7978845608f * (y + 0.044715f * y * y * y);
          float t2 = __expf(-2.f * u);
          float g = __fdividef(y, 1.f + t2);
          outp[(size_t)(row0 + rowb + jj) * N + col] = f2bf(g);
        } else {
          outp[(size_t)(row0 + rowb + jj) * N + col] = f2bf(xv);
        }
      }
    }
  }
}

// out[t][:] = h2[sidx[2t]][:] + h2[sidx[2t+1]][:]   (h2 bf16; out f32)
__global__ void k_reduce(const u16* __restrict__ h2, const int* __restrict__ sidx,
                         float* __restrict__ out) {
  int t = blockIdx.x;
  int c = threadIdx.x;                        // 256 threads x 4 floats = 1024
  const u16* r0 = h2 + (size_t)sidx[2 * t] * HD + c * 4;
  const u16* r1 = h2 + (size_t)sidx[2 * t + 1] * HD + c * 4;
  u16 a0[4], a1[4];
  *(uint2*)a0 = *(const uint2*)r0;
  *(uint2*)a1 = *(const uint2*)r1;
  f4 s;
  #pragma unroll
  for (int jj = 0; jj < 4; ++jj) s[jj] = bf2f(a0[jj]) + bf2f(a1[jj]);
  *(f4*)(out + (size_t)t * HD + c * 4) = s;
}

extern "C" void kernel_launch(void* const* d_in, const int* in_sizes, int n_in,
                              void* d_out, int out_size, void* d_ws, size_t ws_size,
                              hipStream_t stream) {
  const float* inp  = (const float*)d_in[0];
  const float* w1   = (const float*)d_in[1];
  const float* w2   = (const float*)d_in[2];
  const int*   sidx = (const int*)d_in[3];
  float* out = (float*)d_out;

  char* ws   = (char*)d_ws;
  int*   s2t = (int*)ws;                                          // 64 KB
  u16*   X   = (u16*)(ws + (1 << 20));                            // 32 MB bf16 [MTOT][HD]
  u16*   act = (u16*)(ws + (1 << 20) + (32u << 20));              // 64 MB bf16 [MTOT][FFND]
  u16*   h2  = (u16*)(ws + (1 << 20) + (96u << 20));              // 32 MB bf16 [MTOT][HD]

  k_build_s2t<<<MTOT / 256, 256, 0, stream>>>(sidx, s2t);
  k_gather_x<<<(MTOT * (HD / 8)) / 256, 256, 0, stream>>>(inp, s2t, X);
  moe_gemm<HD, FFND, true><<<dim3(FFND / 256, NE), 512, 0, stream>>>(X, w1, act);
  moe_gemm<FFND, HD, false><<<dim3(HD / 256, NE), 512, 0, stream>>>(act, w2, h2);
  k_reduce<<<NTOK, 256, 0, stream>>>(h2, sidx, out);
}